// Round 1
// baseline (1529.977 us; speedup 1.0000x reference)
//
#include <hip/hip_runtime.h>
#include <cstddef>
#include <cmath>

#define FFT_N   512
#define FFT_LOGN 9
#define IMG_PIX (FFT_N * FFT_N)
#define NIMG    48          // B*C = 16*3
#define KSZ     15
#define KK      (KSZ * KSZ)
#define BAL     0.1f
#define TWO_PI  6.283185307179586f

__device__ __forceinline__ int brev9(int i) { return (int)(__brev((unsigned)i) >> 23); }

__device__ __forceinline__ float2 cmul(float2 a, float2 b) {
  return make_float2(a.x * b.x - a.y * b.y, a.x * b.y + a.y * b.x);
}

// 512-point radix-2 DIT FFT in LDS. 256 threads; input must already be loaded
// into lds[] at bit-reversed positions. DIR = -1 forward, +1 inverse
// (unnormalized). tw[] is a 256-entry twiddle scratch (built here).
template <int DIR>
__device__ __forceinline__ void fft512_lds(float2* lds, float2* tw, int t) {
  {
    float ang = (float)DIR * TWO_PI * (float)t / (float)FFT_N;
    float s, c;
    sincosf(ang, &s, &c);
    tw[t] = make_float2(c, s);
  }
  #pragma unroll
  for (int s = 0; s < FFT_LOGN; ++s) {
    __syncthreads();
    int half = 1 << s;
    int j  = t & (half - 1);
    int i0 = ((t >> s) << (s + 1)) + j;
    int i1 = i0 + half;
    float2 w = tw[j << (8 - s)];
    float2 a = lds[i0];
    float2 b = cmul(lds[i1], w);
    lds[i0] = make_float2(a.x + b.x, a.y + b.y);
    lds[i1] = make_float2(a.x - b.x, a.y - b.y);
  }
  // after stage 8, thread t owns lds[t] and lds[t+256] (it wrote them) — no
  // trailing sync needed before the caller reads exactly those two slots.
}

// Forward FFT along rows, reading the real input directly.
__global__ __launch_bounds__(256) void k_fft_rows_fwd(
    const float* __restrict__ y, float2* __restrict__ ws, int imgBase) {
  __shared__ float2 lds[FFT_N];
  __shared__ float2 tw[256];
  int t = threadIdx.x;
  int line = blockIdx.x;             // local_img*512 + row
  int img = line >> 9, row = line & 511;
  const float* src = y + ((size_t)(imgBase + img) * FFT_N + row) * FFT_N;
  float x0 = src[t];
  float x1 = src[t + 256];
  lds[brev9(t)]       = make_float2(x0, 0.f);
  lds[brev9(t + 256)] = make_float2(x1, 0.f);
  fft512_lds<-1>(lds, tw, t);
  float2* dst = ws + (size_t)line * FFT_N;
  dst[t]       = lds[t];
  dst[t + 256] = lds[t + 256];
}

// FFT along columns, in place (strided global access; correctness-first).
template <int DIR>
__global__ __launch_bounds__(256) void k_fft_cols(float2* __restrict__ ws) {
  __shared__ float2 lds[FFT_N];
  __shared__ float2 tw[256];
  int t = threadIdx.x;
  int line = blockIdx.x;             // local_img*512 + col
  int img = line >> 9, col = line & 511;
  float2* base = ws + (size_t)img * IMG_PIX + col;
  lds[brev9(t)]       = base[(size_t)t * FFT_N];
  lds[brev9(t + 256)] = base[(size_t)(t + 256) * FFT_N];
  fft512_lds<DIR>(lds, tw, t);
  base[(size_t)t * FFT_N]         = lds[t];
  base[(size_t)(t + 256) * FFT_N] = lds[t + 256];
}

// Pointwise Wiener: Y[u,v] *= conj(Hf)/(|Hf|^2 + BAL*L^2), with Hf computed
// on the fly via separable 15x15 direct DFT (roll folded into phase) and the
// Laplacian TF computed analytically: L = 4 - 2cos(2pi u/N) - 2cos(2pi v/N).
__global__ __launch_bounds__(256) void k_wiener(
    float2* __restrict__ ws, const float* __restrict__ filters, int imgBase) {
  __shared__ float  fs[KK];
  __shared__ float2 tw[FFT_N];
  int t = threadIdx.x;
  int line = blockIdx.x;             // local_img*512 + u
  int img = line >> 9, u = line & 511;
  const float* f = filters + (size_t)(imgBase + img) * KK;
  if (t < KK) fs[t] = f[t];
  for (int k = t; k < FFT_N; k += 256) {
    float s, c;
    sincosf(-TWO_PI * (float)k / (float)FFT_N, &s, &c);
    tw[k] = make_float2(c, s);
  }
  __syncthreads();
  float lapu = 2.f - 2.f * cosf(TWO_PI * (float)u / (float)FFT_N);
  float2* rowp = ws + (size_t)line * FFT_N;
  for (int v = t; v < FFT_N; v += 256) {
    float2 H = make_float2(0.f, 0.f);
    #pragma unroll
    for (int i = 0; i < KSZ; ++i) {
      float2 S = make_float2(0.f, 0.f);
      #pragma unroll
      for (int j = 0; j < KSZ; ++j) {
        float2 w = tw[(v * (j - 7)) & 511];
        float fv = fs[i * KSZ + j];
        S.x += fv * w.x;
        S.y += fv * w.y;
      }
      float2 wi = tw[(u * (i - 7)) & 511];
      float2 Si = cmul(S, wi);
      H.x += Si.x;
      H.y += Si.y;
    }
    float lap = lapu + 2.f - 2.f * cosf(TWO_PI * (float)v / (float)FFT_N);
    float denom = H.x * H.x + H.y * H.y + BAL * lap * lap;
    float inv = 1.f / denom;
    float2 Wf = make_float2(H.x * inv, -H.y * inv);
    rowp[v] = cmul(Wf, rowp[v]);
  }
}

// Inverse FFT along rows fused with 1/N^2 scaling, clip, real-part store.
__global__ __launch_bounds__(256) void k_fft_rows_inv_store(
    const float2* __restrict__ ws, float* __restrict__ out, int imgBase) {
  __shared__ float2 lds[FFT_N];
  __shared__ float2 tw[256];
  int t = threadIdx.x;
  int line = blockIdx.x;             // local_img*512 + row
  int img = line >> 9, row = line & 511;
  const float2* src = ws + (size_t)line * FFT_N;
  lds[brev9(t)]       = src[t];
  lds[brev9(t + 256)] = src[t + 256];
  fft512_lds<1>(lds, tw, t);
  float* dst = out + ((size_t)(imgBase + img) * FFT_N + row) * FFT_N;
  const float scale = 1.f / (float)IMG_PIX;
  float v0 = lds[t].x * scale;
  float v1 = lds[t + 256].x * scale;
  dst[t]       = fminf(1.f, fmaxf(-1.f, v0));
  dst[t + 256] = fminf(1.f, fmaxf(-1.f, v1));
}

extern "C" void kernel_launch(void* const* d_in, const int* in_sizes, int n_in,
                              void* d_out, int out_size, void* d_ws, size_t ws_size,
                              hipStream_t stream) {
  const float* y       = (const float*)d_in[0];
  const float* filters = (const float*)d_in[1];
  float* out = (float*)d_out;
  float2* ws = (float2*)d_ws;

  size_t perImg = (size_t)IMG_PIX * sizeof(float2);   // 2 MiB per image
  int chunk = (int)(ws_size / perImg);
  if (chunk > NIMG) chunk = NIMG;
  if (chunk < 1)   chunk = 1;                          // hope ws >= 2 MiB

  for (int b0 = 0; b0 < NIMG; b0 += chunk) {
    int nc = (chunk < NIMG - b0) ? chunk : (NIMG - b0);
    int lines = nc * FFT_N;
    k_fft_rows_fwd     <<<lines, 256, 0, stream>>>(y, ws, b0);
    k_fft_cols<-1>     <<<lines, 256, 0, stream>>>(ws);
    k_wiener           <<<lines, 256, 0, stream>>>(ws, filters, b0);
    k_fft_cols<1>      <<<lines, 256, 0, stream>>>(ws);
    k_fft_rows_inv_store<<<lines, 256, 0, stream>>>(ws, out, b0);
  }
}

// Round 2
// 544.982 us; speedup vs baseline: 2.8074x; 2.8074x over previous
//
#include <hip/hip_runtime.h>
#include <cstddef>
#include <cmath>

#define FFT_N    512
#define FFT_LOGN 9
#define IMG_PIX  (FFT_N * FFT_N)
#define NIMG     48          // B*C = 16*3
#define NPAIR    24          // images packed two-per-complex-FFT
#define KSZ      15
#define KK       (KSZ * KSZ)
#define BAL      0.1f
#define TWO_PI   6.283185307179586f

__device__ __forceinline__ int brev9(int i) { return (int)(__brev((unsigned)i) >> 23); }

__device__ __forceinline__ float2 cmul(float2 a, float2 b) {
  return make_float2(a.x * b.x - a.y * b.y, a.x * b.y + a.y * b.x);
}

// 512-point radix-2 DIT FFT in LDS. 256 threads; input must already be loaded
// into lds[] at bit-reversed positions. DIR = -1 forward, +1 inverse
// (unnormalized). tw[] is a 256-entry twiddle scratch (built here).
template <int DIR>
__device__ __forceinline__ void fft512_lds(float2* lds, float2* tw, int t) {
  {
    float ang = (float)DIR * TWO_PI * (float)t / (float)FFT_N;
    float s, c;
    sincosf(ang, &s, &c);
    tw[t] = make_float2(c, s);
  }
  #pragma unroll
  for (int s = 0; s < FFT_LOGN; ++s) {
    __syncthreads();
    int half = 1 << s;
    int j  = t & (half - 1);
    int i0 = ((t >> s) << (s + 1)) + j;
    int i1 = i0 + half;
    float2 w = tw[j << (8 - s)];
    float2 a = lds[i0];
    float2 b = cmul(lds[i1], w);
    lds[i0] = make_float2(a.x + b.x, a.y + b.y);
    lds[i1] = make_float2(a.x - b.x, a.y - b.y);
  }
  // after the last stage thread t wrote lds[t] and lds[t+256]; callers reading
  // exactly those two slots need no trailing sync.
}

// Separable PSF row-DFT: S[img][i][v] = sum_j f[i][j] * e^{-2pi i v(j-7)/512}.
__global__ __launch_bounds__(256) void k_psf_rows(
    const float* __restrict__ filters, float2* __restrict__ S) {
  __shared__ float fs[KSZ];
  int blk = blockIdx.x;          // img*15 + i
  int img = blk / KSZ, i = blk % KSZ;
  int t = threadIdx.x;
  if (t < KSZ) fs[t] = filters[(size_t)img * KK + i * KSZ + t];
  __syncthreads();
  for (int v = t; v < FFT_N; v += 256) {
    float2 s = make_float2(0.f, 0.f);
    #pragma unroll
    for (int j = 0; j < KSZ; ++j) {
      float ang = -TWO_PI * (float)(v * (j - 7)) / (float)FFT_N;
      float sn, cs;
      sincosf(ang, &sn, &cs);
      s.x += fs[j] * cs;
      s.y += fs[j] * sn;
    }
    S[((size_t)img * KSZ + i) * FFT_N + v] = s;
  }
}

// Forward row FFT of a packed image pair: z = yA + i*yB.
__global__ __launch_bounds__(256) void k_fft_rows_fwd_pair(
    const float* __restrict__ y, float2* __restrict__ ws, int pairBase) {
  __shared__ float2 lds[FFT_N];
  __shared__ float2 tw[256];
  int t = threadIdx.x;
  int line = blockIdx.x;             // localPair*512 + row
  int p = line >> 9, row = line & 511;
  int gp = pairBase + p;
  const float* srcA = y + ((size_t)(2 * gp) * FFT_N + row) * FFT_N;
  const float* srcB = srcA + (size_t)IMG_PIX;
  lds[brev9(t)]       = make_float2(srcA[t],       srcB[t]);
  lds[brev9(t + 256)] = make_float2(srcA[t + 256], srcB[t + 256]);
  fft512_lds<-1>(lds, tw, t);
  float2* dst = ws + (size_t)line * FFT_N;
  dst[t]       = lds[t];
  dst[t + 256] = lds[t + 256];
}

// FFT along columns, in place (strided global access).
template <int DIR>
__global__ __launch_bounds__(256) void k_fft_cols(float2* __restrict__ ws) {
  __shared__ float2 lds[FFT_N];
  __shared__ float2 tw[256];
  int t = threadIdx.x;
  int line = blockIdx.x;             // localPair*512 + col
  int p = line >> 9, col = line & 511;
  float2* base = ws + (size_t)p * IMG_PIX + col;
  lds[brev9(t)]       = base[(size_t)t * FFT_N];
  lds[brev9(t + 256)] = base[(size_t)(t + 256) * FFT_N];
  fft512_lds<DIR>(lds, tw, t);
  base[(size_t)t * FFT_N]         = lds[t];
  base[(size_t)(t + 256) * FFT_N] = lds[t + 256];
}

// Pointwise Wiener on a packed pair: unpack Hermitian halves, apply each
// image's Wiener filter (H via separable S + per-row phase), repack.
// Block = (localPair, u) with u in [0,256]; row u pairs with u2=(512-u)&511.
__global__ __launch_bounds__(256) void k_wiener_pair(
    float2* __restrict__ ws, const float2* __restrict__ S,
    const float2* __restrict__ Sdummy, int pairBase) {
  __shared__ float2 cu[KSZ];         // e^{-2pi i u(i-7)/512}
  int t = threadIdx.x;
  int blk = blockIdx.x;              // localPair*257 + u
  int p = blk / 257, u = blk % 257;
  int u2 = (FFT_N - u) & 511;
  int gp = pairBase + p;
  const float2* SA = S + (size_t)(2 * gp) * KSZ * FFT_N;
  const float2* SB = SA + (size_t)KSZ * FFT_N;
  if (t < KSZ) {
    float ang = -TWO_PI * (float)(u * (t - 7)) / (float)FFT_N;
    float sn, cs;
    sincosf(ang, &sn, &cs);
    cu[t] = make_float2(cs, sn);
  }
  __syncthreads();
  float lapu = 2.f - 2.f * cosf(TWO_PI * (float)u / (float)FFT_N);
  float2* Zu  = ws + ((size_t)p * FFT_N + u)  * FFT_N;
  float2* Zu2 = ws + ((size_t)p * FFT_N + u2) * FFT_N;
  // Self-paired rows (u==u2): primary v restricted to [0,256] so each thread
  // reads and writes only its own two slots (no cross-thread hazard).
  int vmax = (u == u2) ? 257 : FFT_N;
  for (int v = t; v < vmax; v += 256) {
    int v2 = (FFT_N - v) & 511;
    float2 HA = make_float2(0.f, 0.f), HB = make_float2(0.f, 0.f);
    #pragma unroll
    for (int i = 0; i < KSZ; ++i) {
      float2 c  = cu[i];
      float2 sa = SA[i * FFT_N + v];
      float2 sb = SB[i * FFT_N + v];
      HA.x += c.x * sa.x - c.y * sa.y;
      HA.y += c.x * sa.y + c.y * sa.x;
      HB.x += c.x * sb.x - c.y * sb.y;
      HB.y += c.x * sb.y + c.y * sb.x;
    }
    float lap = lapu + 2.f - 2.f * cosf(TWO_PI * (float)v / (float)FFT_N);
    float l2 = BAL * lap * lap;
    float invA = 1.f / (HA.x * HA.x + HA.y * HA.y + l2);
    float invB = 1.f / (HB.x * HB.x + HB.y * HB.y + l2);
    float2 Zp = Zu[v];
    float2 Zm = Zu2[v2];
    // Y1 = 0.5(Zp + conj(Zm)); Y2 = -0.5i(Zp - conj(Zm))
    float2 Y1 = make_float2(0.5f * (Zp.x + Zm.x),  0.5f * (Zp.y - Zm.y));
    float2 Y2 = make_float2(0.5f * (Zp.y + Zm.y), -0.5f * (Zp.x - Zm.x));
    // a = conj(HA)*Y1*invA ; b = conj(HB)*Y2*invB
    float2 a = make_float2((HA.x * Y1.x + HA.y * Y1.y) * invA,
                           (HA.x * Y1.y - HA.y * Y1.x) * invA);
    float2 b = make_float2((HB.x * Y2.x + HB.y * Y2.y) * invB,
                           (HB.x * Y2.y - HB.y * Y2.x) * invB);
    // Z'(u,v) = a + i b ; Z'(u2,v2) = conj(a) + i conj(b)
    Zu[v]   = make_float2(a.x - b.y, a.y + b.x);
    Zu2[v2] = make_float2(a.x + b.y, b.x - a.y);
  }
}

// Inverse row FFT fused with 1/N^2 scale, clip, and unpack to two real images.
__global__ __launch_bounds__(256) void k_fft_rows_inv_pair(
    const float2* __restrict__ ws, float* __restrict__ out, int pairBase) {
  __shared__ float2 lds[FFT_N];
  __shared__ float2 tw[256];
  int t = threadIdx.x;
  int line = blockIdx.x;             // localPair*512 + row
  int p = line >> 9, row = line & 511;
  int gp = pairBase + p;
  const float2* src = ws + (size_t)line * FFT_N;
  lds[brev9(t)]       = src[t];
  lds[brev9(t + 256)] = src[t + 256];
  fft512_lds<1>(lds, tw, t);
  float* dstA = out + ((size_t)(2 * gp) * FFT_N + row) * FFT_N;
  float* dstB = dstA + (size_t)IMG_PIX;
  const float scale = 1.f / (float)IMG_PIX;
  float2 r0 = lds[t], r1 = lds[t + 256];
  dstA[t]       = fminf(1.f, fmaxf(-1.f, r0.x * scale));
  dstA[t + 256] = fminf(1.f, fmaxf(-1.f, r1.x * scale));
  dstB[t]       = fminf(1.f, fmaxf(-1.f, r0.y * scale));
  dstB[t + 256] = fminf(1.f, fmaxf(-1.f, r1.y * scale));
}

extern "C" void kernel_launch(void* const* d_in, const int* in_sizes, int n_in,
                              void* d_out, int out_size, void* d_ws, size_t ws_size,
                              hipStream_t stream) {
  const float* y       = (const float*)d_in[0];
  const float* filters = (const float*)d_in[1];
  float* out = (float*)d_out;

  // ws layout: [S: 48*15*512 float2 = 2.95 MB][Z: chunk pairs * 2 MiB]
  size_t sBytes = (size_t)NIMG * KSZ * FFT_N * sizeof(float2);
  float2* S = (float2*)d_ws;
  float2* Z = (float2*)((char*)d_ws + sBytes);
  size_t zBytes = (ws_size > sBytes) ? (ws_size - sBytes) : 0;

  size_t perPair = (size_t)IMG_PIX * sizeof(float2);   // 2 MiB
  int chunk = (int)(zBytes / perPair);
  if (chunk > NPAIR) chunk = NPAIR;
  if (chunk < 1)     chunk = 1;

  k_psf_rows<<<NIMG * KSZ, 256, 0, stream>>>(filters, S);

  for (int p0 = 0; p0 < NPAIR; p0 += chunk) {
    int nc = (chunk < NPAIR - p0) ? chunk : (NPAIR - p0);
    int lines = nc * FFT_N;
    k_fft_rows_fwd_pair<<<lines, 256, 0, stream>>>(y, Z, p0);
    k_fft_cols<-1>     <<<lines, 256, 0, stream>>>(Z);
    k_wiener_pair      <<<nc * 257, 256, 0, stream>>>(Z, S, S, p0);
    k_fft_cols<1>      <<<lines, 256, 0, stream>>>(Z);
    k_fft_rows_inv_pair<<<lines, 256, 0, stream>>>(Z, out, p0);
  }
}

// Round 3
// 289.325 us; speedup vs baseline: 5.2881x; 1.8836x over previous
//
#include <hip/hip_runtime.h>
#include <cstddef>
#include <cmath>

#define FFT_N    512
#define FFT_LOGN 9
#define IMG_PIX  (FFT_N * FFT_N)
#define NIMG     48          // B*C
#define NPAIR    24
#define KSZ      15
#define KK       (KSZ * KSZ)
#define BAL      0.1f
#define TWO_PI   6.283185307179586f
#define NV       257         // rfft half-width (v = 0..256)
#define LDP      513         // padded LDS row stride in float2 (+1 to break banks)
#define TILE_R   16

__device__ __forceinline__ int brev9(int i) { return (int)(__brev((unsigned)i) >> 23); }

__device__ __forceinline__ float2 cmul(float2 a, float2 b) {
  return make_float2(a.x * b.x - a.y * b.y, a.x * b.y + a.y * b.x);
}
__device__ __forceinline__ float2 cmulc(float2 a, float2 b) {  // a * conj(b)
  return make_float2(a.x * b.x + a.y * b.y, a.y * b.x - a.x * b.y);
}

// 16 x 512-pt forward DIF FFT in LDS: natural-order input, bit-reversed output.
// Thread t: sequence f = t>>4, butterflies (t&15)+16k. tw[k]=e^{-2pi i k/512}.
__device__ __forceinline__ void dif16(float2* lds, const float2* tw, int t) {
  int f = t >> 4, bb = t & 15;
  float2* base = lds + f * LDP;
  for (int s = FFT_LOGN - 1; s >= 0; --s) {
    __syncthreads();
    int half = 1 << s;
    #pragma unroll
    for (int k = 0; k < 16; ++k) {
      int b = bb + (k << 4);
      int j = b & (half - 1);
      int i0 = ((b >> s) << (s + 1)) + j;
      float2 a = base[i0], c = base[i0 + half];
      float2 w = tw[j << (8 - s)];
      base[i0] = make_float2(a.x + c.x, a.y + c.y);
      base[i0 + half] = cmul(make_float2(a.x - c.x, a.y - c.y), w);
    }
  }
  __syncthreads();
}

// 16 x 512-pt inverse DIT FFT in LDS: bit-reversed input, natural output
// (unnormalized). Uses conj(tw) inline (tw[k]=e^{-2pi i k/512}).
__device__ __forceinline__ void dit16_inv(float2* lds, const float2* tw, int t) {
  int f = t >> 4, bb = t & 15;
  float2* base = lds + f * LDP;
  for (int s = 0; s < FFT_LOGN; ++s) {
    __syncthreads();
    int half = 1 << s;
    #pragma unroll
    for (int k = 0; k < 16; ++k) {
      int b = bb + (k << 4);
      int j = b & (half - 1);
      int i0 = ((b >> s) << (s + 1)) + j;
      float2 a = base[i0];
      float2 bw = cmulc(base[i0 + half], tw[j << (8 - s)]);
      base[i0] = make_float2(a.x + bw.x, a.y + bw.y);
      base[i0 + half] = make_float2(a.x - bw.x, a.y - bw.y);
    }
  }
  __syncthreads();
}

// Separable PSF row-DFT: S[img][i][v] = sum_j f[i][j] * e^{-2pi i v(j-7)/512}.
__global__ __launch_bounds__(256) void k_psf_rows(
    const float* __restrict__ filters, float2* __restrict__ S) {
  __shared__ float fs[KSZ];
  int blk = blockIdx.x;          // img*15 + i
  int img = blk / KSZ, i = blk % KSZ;
  int t = threadIdx.x;
  if (t < KSZ) fs[t] = filters[(size_t)img * KK + i * KSZ + t];
  __syncthreads();
  for (int v = t; v < FFT_N; v += 256) {
    float2 s = make_float2(0.f, 0.f);
    #pragma unroll
    for (int j = 0; j < KSZ; ++j) {
      float ang = -TWO_PI * (float)(v * (j - 7)) / (float)FFT_N;
      float sn, cs;
      sincosf(ang, &sn, &cs);
      s.x += fs[j] * cs;
      s.y += fs[j] * sn;
    }
    S[((size_t)img * KSZ + i) * FFT_N + v] = s;
  }
}

// Row FFT of packed pair (z = yA + i yB), 16 rows per block, then Hermitian
// unpack to the two half-spectra and TRANSPOSED store: zh[img][v][row].
__global__ __launch_bounds__(256) void k_rows_fwd(
    const float* __restrict__ y, float2* __restrict__ zh, int pairBase) {
  __shared__ float2 lds[TILE_R * LDP];
  __shared__ float2 tw[256];
  int t = threadIdx.x;
  int blk = blockIdx.x;
  int p = blk >> 5, rg = blk & 31;         // local pair, row-group
  int gp = pairBase + p;
  {
    float ang = -TWO_PI * (float)t / (float)FFT_N;
    float s, c; sincosf(ang, &s, &c); tw[t] = make_float2(c, s);
  }
  const float* srcA = y + (size_t)(2 * gp) * IMG_PIX + (size_t)rg * TILE_R * FFT_N;
  const float* srcB = srcA + IMG_PIX;
  #pragma unroll 4
  for (int m = 0; m < 32; ++m) {
    int idx = t + (m << 8);
    int r = idx >> 9, cp = idx & 511;
    lds[r * LDP + cp] = make_float2(srcA[idx], srcB[idx]);
  }
  dif16(lds, tw, t);
  float2* zA = zh + (size_t)(2 * p) * NV * FFT_N;   // chunk-local indexing
  float2* zB = zA + (size_t)NV * FFT_N;
  int r = t & 15, vv = t >> 4;
  int rowg = rg * TILE_R + r;
  for (int m = 0; m <= 16; ++m) {
    int v = vv + (m << 4);
    if (v > 256) break;
    float2 Zp = lds[r * LDP + brev9(v)];
    float2 Zm = lds[r * LDP + brev9((FFT_N - v) & 511)];
    float2 ya = make_float2(0.5f * (Zp.x + Zm.x), 0.5f * (Zp.y - Zm.y));
    float2 yb = make_float2(0.5f * (Zp.y + Zm.y), 0.5f * (Zm.x - Zp.x));
    zA[(size_t)v * FFT_N + rowg] = ya;
    zB[(size_t)v * FFT_N + rowg] = yb;
  }
}

// Fused: forward column FFT + pointwise Wiener + inverse column FFT.
// Columns are CONTIGUOUS in zh[img][v][row]; 16 columns per block stay in LDS.
__global__ __launch_bounds__(256) void k_col_wiener(
    float2* __restrict__ zh, const float2* __restrict__ S, int imgBase) {
  __shared__ float2 lds[TILE_R * LDP];
  __shared__ float2 twf[512];
  __shared__ float2 Sv[16][KSZ];
  int t = threadIdx.x;
  int img_l = blockIdx.x / 17, g = blockIdx.x % 17;
  int img = imgBase + img_l;
  int vbase = g * 16;
  int ncols = (g == 16) ? 1 : 16;
  {
    float s, c;
    float ang = -TWO_PI * (float)t / (float)FFT_N;
    sincosf(ang, &s, &c); twf[t] = make_float2(c, s);
    float ang2 = -TWO_PI * (float)(t + 256) / (float)FFT_N;
    sincosf(ang2, &s, &c); twf[t + 256] = make_float2(c, s);
  }
  float2* zc = zh + ((size_t)img_l * NV + vbase) * FFT_N;
  int nelem = ncols * FFT_N;
  for (int idx = t; idx < nelem; idx += 256)
    lds[(idx >> 9) * LDP + (idx & 511)] = zc[idx];
  {
    int c = t >> 4, i = t & 15;
    if (i < KSZ && c < ncols)
      Sv[c][i] = S[((size_t)img * KSZ + i) * FFT_N + vbase + c];
  }
  dif16(lds, twf, t);          // internal barriers also cover twf/Sv visibility
  // Wiener in bit-reversed u domain: slot su holds frequency u = brev9(su).
  #pragma unroll
  for (int pass = 0; pass < 2; ++pass) {
    int su = t + (pass << 8);
    int u = brev9(su);
    float2 wu = twf[u];
    float lu = 2.f - 2.f * wu.x;                  // Laplacian u-term
    float2 cu[KSZ];
    float2 c7 = twf[(7 * u) & 511];
    cu[0] = make_float2(c7.x, -c7.y);             // e^{+2pi i 7u/512}
    #pragma unroll
    for (int i = 1; i < KSZ; ++i) cu[i] = cmul(cu[i - 1], wu);
    for (int c = 0; c < ncols; ++c) {
      float2 H = make_float2(0.f, 0.f);
      #pragma unroll
      for (int i = 0; i < KSZ; ++i) {
        float2 s0 = Sv[c][i];
        H.x += cu[i].x * s0.x - cu[i].y * s0.y;
        H.y += cu[i].x * s0.y + cu[i].y * s0.x;
      }
      int v = vbase + c;
      float lv = 2.f - 2.f * twf[v].x;
      float lap = lu + lv;
      float denom = H.x * H.x + H.y * H.y + BAL * lap * lap;
      float inv = 1.f / denom;
      float2 Z = lds[c * LDP + su];
      float2 W = make_float2(H.x * inv, -H.y * inv);
      lds[c * LDP + su] = cmul(W, Z);
    }
  }
  dit16_inv(lds, twf, t);      // leading barrier covers the Wiener writes
  for (int idx = t; idx < nelem; idx += 256)
    zc[idx] = lds[(idx >> 9) * LDP + (idx & 511)];
}

// Repack full row spectra from the two half-spectra (Hermitian in v), inverse
// row FFT, scale + clip + store both real images.
__global__ __launch_bounds__(256) void k_rows_inv(
    const float2* __restrict__ zh, float* __restrict__ out, int pairBase) {
  __shared__ float2 lds[TILE_R * LDP];
  __shared__ float2 tw[256];
  int t = threadIdx.x;
  int blk = blockIdx.x;
  int p = blk >> 5, rg = blk & 31;
  int gp = pairBase + p;
  {
    float ang = -TWO_PI * (float)t / (float)FFT_N;
    float s, c; sincosf(ang, &s, &c); tw[t] = make_float2(c, s);
  }
  const float2* zA = zh + (size_t)(2 * p) * NV * FFT_N;
  const float2* zB = zA + (size_t)NV * FFT_N;
  int r = t & 15, vv = t >> 4;
  int rowg = rg * TILE_R + r;
  for (int m = 0; m <= 16; ++m) {
    int v = vv + (m << 4);
    if (v > 256) break;
    float2 ya = zA[(size_t)v * FFT_N + rowg];
    float2 yb = zB[(size_t)v * FFT_N + rowg];
    // Z(v) = YA + i YB   (store at bit-reversed slot for the DIT inverse)
    lds[r * LDP + brev9(v)] = make_float2(ya.x - yb.y, ya.y + yb.x);
    if (v >= 1 && v <= 255) {
      // Z(512-v) = conj(YA) + i conj(YB)
      lds[r * LDP + brev9(FFT_N - v)] = make_float2(ya.x + yb.y, yb.x - ya.y);
    }
  }
  dit16_inv(lds, tw, t);       // leading barrier covers the assembly writes
  float* dstA = out + (size_t)(2 * gp) * IMG_PIX + (size_t)rg * TILE_R * FFT_N;
  float* dstB = dstA + IMG_PIX;
  const float sc = 1.f / (float)IMG_PIX;
  #pragma unroll 4
  for (int m = 0; m < 32; ++m) {
    int idx = t + (m << 8);
    float2 zv = lds[(idx >> 9) * LDP + (idx & 511)];
    dstA[idx] = fminf(1.f, fmaxf(-1.f, zv.x * sc));
    dstB[idx] = fminf(1.f, fmaxf(-1.f, zv.y * sc));
  }
}

extern "C" void kernel_launch(void* const* d_in, const int* in_sizes, int n_in,
                              void* d_out, int out_size, void* d_ws, size_t ws_size,
                              hipStream_t stream) {
  const float* y       = (const float*)d_in[0];
  const float* filters = (const float*)d_in[1];
  float* out = (float*)d_out;

  // ws layout: [S: 48*15*512 float2 = 2.95 MB][zh: chunk*2 images * 257*512 f2]
  size_t sElems = (size_t)NIMG * KSZ * FFT_N;
  float2* S  = (float2*)d_ws;
  float2* zh = S + sElems;
  size_t sBytes = sElems * sizeof(float2);
  size_t zBytes = (ws_size > sBytes) ? (ws_size - sBytes) : 0;
  size_t perPair = (size_t)2 * NV * FFT_N * sizeof(float2);   // ~2.1 MiB
  int chunk = (int)(zBytes / perPair);
  if (chunk > NPAIR) chunk = NPAIR;
  if (chunk < 1)     chunk = 1;

  k_psf_rows<<<NIMG * KSZ, 256, 0, stream>>>(filters, S);

  for (int p0 = 0; p0 < NPAIR; p0 += chunk) {
    int nc = (chunk < NPAIR - p0) ? chunk : (NPAIR - p0);
    k_rows_fwd  <<<nc * 32,     256, 0, stream>>>(y, zh, p0);
    k_col_wiener<<<2 * nc * 17, 256, 0, stream>>>(zh, S, 2 * p0);
    k_rows_inv  <<<nc * 32,     256, 0, stream>>>(zh, out, p0);
  }
}

// Round 4
// 260.504 us; speedup vs baseline: 5.8731x; 1.1106x over previous
//
#include <hip/hip_runtime.h>
#include <cstddef>
#include <cmath>

#define FFT_N    512
#define IMG_PIX  (FFT_N * FFT_N)
#define NIMG     48          // B*C
#define NPAIR    24
#define KSZ      15
#define KK       (KSZ * KSZ)
#define BAL      0.1f
#define TWO_PI   6.283185307179586f
#define NV       257                         // rfft half-width (v = 0..256)
#define PLANE    ((size_t)FFT_N * NV)        // elems per image half-spectrum plane
#define EXSZ     576                         // per-wave exchange buffer (floats)

__device__ __forceinline__ float2 cadd(float2 a, float2 b) { return make_float2(a.x + b.x, a.y + b.y); }
__device__ __forceinline__ float2 csub(float2 a, float2 b) { return make_float2(a.x - b.x, a.y - b.y); }
__device__ __forceinline__ float2 cmul(float2 a, float2 b) {
  return make_float2(a.x * b.x - a.y * b.y, a.x * b.y + a.y * b.x);
}
__device__ __forceinline__ int ex1(int c, int b, int g) { return 72 * c + 8 * b + g; }
__device__ __forceinline__ int ex2(int c, int e, int g) { return 72 * c + 9 * e + g; }

// DFT8 over the 8 registers: out[k] = sum_a in[a] e^{-+2pi i a k/8} (INV => +).
template <bool INV>
__device__ __forceinline__ void dft8(float2 r[8]) {
  const float RH = 0.70710678118654752440f;
  float2 s0 = cadd(r[0], r[4]), s1 = cadd(r[1], r[5]), s2 = cadd(r[2], r[6]), s3 = cadd(r[3], r[7]);
  float2 d0 = csub(r[0], r[4]), d1 = csub(r[1], r[5]), d2 = csub(r[2], r[6]), d3 = csub(r[3], r[7]);
  if (!INV) {
    d1 = make_float2(RH * (d1.x + d1.y), RH * (d1.y - d1.x));   // *W8^1
    d2 = make_float2(d2.y, -d2.x);                              // *-i
    d3 = make_float2(RH * (d3.y - d3.x), RH * (-d3.x - d3.y));  // *W8^3
  } else {
    d1 = make_float2(RH * (d1.x - d1.y), RH * (d1.x + d1.y));   // *W8^-1
    d2 = make_float2(-d2.y, d2.x);                              // *+i
    d3 = make_float2(RH * (-d3.x - d3.y), RH * (d3.x - d3.y));  // *W8^-3
  }
  float2 t0 = cadd(s0, s2), t1 = csub(s0, s2), t2 = cadd(s1, s3), t3 = csub(s1, s3);
  t3 = INV ? make_float2(-t3.y, t3.x) : make_float2(t3.y, -t3.x);
  float2 E0 = cadd(t0, t2), E1 = cadd(t1, t3), E2 = csub(t0, t2), E3 = csub(t1, t3);
  t0 = cadd(d0, d2); t1 = csub(d0, d2); t2 = cadd(d1, d3); t3 = csub(d1, d3);
  t3 = INV ? make_float2(-t3.y, t3.x) : make_float2(t3.y, -t3.x);
  r[0] = E0; r[2] = E1; r[4] = E2; r[6] = E3;
  r[1] = cadd(t0, t2); r[3] = cadd(t1, t3); r[5] = csub(t0, t2); r[7] = csub(t1, t3);
}

// 512-pt FFT, one wave per line, data in 8 regs. tw[k] = e^{-2pi i k/512}.
// Forward (INV=false): input r[a] = x[64a + j] -> output at lane 8c+e, reg f
//   holding X[c + 8e + 64f]  (equivalently: bitswap-lanes => lane-linear).
// Inverse (INV=true): conjugate graph; input r[a] = X[64a + j] (lane-linear k),
//   output x[c+8e+64f] at lane 8c+e reg f (bitswap => lane-linear pixels).
template <bool INV>
__device__ void fft512_reg(float2 r[8], float* ere, float* eim, const float2* tw, int j) {
  const int hi = j >> 3, lo = j & 7;
  dft8<INV>(r);                         // over a -> regs c   (roles b=hi, g=lo)
  #pragma unroll
  for (int c = 1; c < 8; ++c) {         // twiddle W64^{b c}
    float2 w = tw[(8 * hi * c) & 511];
    if (INV) w.y = -w.y;
    r[c] = cmul(r[c], w);
  }
  #pragma unroll
  for (int c = 0; c < 8; ++c) { int a = ex1(c, hi, lo); ere[a] = r[c].x; eim[a] = r[c].y; }
  __syncthreads();
  #pragma unroll
  for (int b = 0; b < 8; ++b) { int a = ex1(hi, b, lo); r[b] = make_float2(ere[a], eim[a]); }
  dft8<INV>(r);                         // over b -> regs e   (roles c=hi, g=lo)
  {                                     // twiddle W512^{g(c+8e)} via recurrence
    float2 base = tw[(lo * hi) & 511];
    float2 step = tw[(8 * lo) & 511];
    if (INV) { base.y = -base.y; step.y = -step.y; }
    #pragma unroll
    for (int e = 0; e < 8; ++e) { r[e] = cmul(r[e], base); base = cmul(base, step); }
  }
  __syncthreads();                      // waves may still be reading ex1 slots
  #pragma unroll
  for (int e = 0; e < 8; ++e) { int a = ex2(hi, e, lo); ere[a] = r[e].x; eim[a] = r[e].y; }
  __syncthreads();
  #pragma unroll
  for (int g = 0; g < 8; ++g) { int a = ex2(hi, lo, g); r[g] = make_float2(ere[a], eim[a]); }
  dft8<INV>(r);                         // over g -> regs f   (roles c=hi, e=lo)
}

// lane bit-swap (hi3<->lo3): converts (c,e)-lane layout <-> lane-linear layout.
__device__ __forceinline__ void bitswap_lanes(float2 r[8], int j) {
  int src = ((j & 7) << 3) | (j >> 3);
  #pragma unroll
  for (int f = 0; f < 8; ++f) {
    r[f].x = __shfl(r[f].x, src);
    r[f].y = __shfl(r[f].y, src);
  }
}

__device__ __forceinline__ void fill_tw(float2* tw, int t) {
  float s, c;
  float ang = -TWO_PI * (float)t / (float)FFT_N;
  sincosf(ang, &s, &c); tw[t] = make_float2(c, s);
  ang = -TWO_PI * (float)(t + 256) / (float)FFT_N;
  sincosf(ang, &s, &c); tw[t + 256] = make_float2(c, s);
}

// Separable PSF row-DFT: S[img][i][v] = sum_j f[i][j] e^{-2pi i v(j-7)/512}.
__global__ __launch_bounds__(256) void k_psf_rows(
    const float* __restrict__ filters, float2* __restrict__ S) {
  __shared__ float fs[KSZ];
  int blk = blockIdx.x;          // img*15 + i
  int img = blk / KSZ, i = blk % KSZ;
  int t = threadIdx.x;
  if (t < KSZ) fs[t] = filters[(size_t)img * KK + i * KSZ + t];
  __syncthreads();
  for (int v = t; v < FFT_N; v += 256) {
    float2 s = make_float2(0.f, 0.f);
    #pragma unroll
    for (int j = 0; j < KSZ; ++j) {
      float ang = -TWO_PI * (float)(v * (j - 7)) / (float)FFT_N;
      float sn, cs;
      sincosf(ang, &sn, &cs);
      s.x += fs[j] * cs;
      s.y += fs[j] * sn;
    }
    S[((size_t)img * KSZ + i) * FFT_N + v] = s;
  }
}

// Row FFT of packed pair (z = yA + i yB) + Hermitian unpack; writes per-image
// half-spectrum planes zh1[img][row][v], v in [0,256]. One wave per row.
__global__ __launch_bounds__(256) void k_rows_fwd(
    const float* __restrict__ y, float2* __restrict__ zh1, int pairBase) {
  __shared__ float ere[4][EXSZ], eim[4][EXSZ];
  __shared__ float2 tw[512];
  int t = threadIdx.x, w = t >> 6, j = t & 63;
  fill_tw(tw, t);
  __syncthreads();
  int p = blockIdx.x >> 5, bg = blockIdx.x & 31;
  int gp = pairBase + p;
  const float* baseA = y + (size_t)(2 * gp) * IMG_PIX;
  const float* baseB = baseA + IMG_PIX;
  float2* plA = zh1 + (size_t)(2 * p) * PLANE;   // chunk-local planes
  float2* plB = plA + PLANE;
  for (int q = 0; q < 4; ++q) {
    int row = bg * 16 + q * 4 + w;
    const float* rA = baseA + (size_t)row * FFT_N;
    const float* rB = baseB + (size_t)row * FFT_N;
    float2 r[8];
    #pragma unroll
    for (int a = 0; a < 8; ++a) r[a] = make_float2(rA[64 * a + j], rB[64 * a + j]);
    fft512_reg<false>(r, ere[w], eim[w], tw, j);
    bitswap_lanes(r, j);                 // lane j reg f  <->  Z[64f + j]
    float2 m[8];
    int msrc = (64 - j) & 63;
    #pragma unroll
    for (int f = 0; f < 8; ++f) { m[f].x = __shfl(r[f].x, msrc); m[f].y = __shfl(r[f].y, msrc); }
    float2* wA = plA + (size_t)row * NV;
    float2* wB = plB + (size_t)row * NV;
    #pragma unroll
    for (int f = 0; f < 5; ++f) {
      int v = 64 * f + j;
      float2 Zp = r[f];
      float2 Zm = (j == 0) ? m[(8 - f) & 7] : m[7 - f];   // Z[(512 - v) & 511]
      float2 ya = make_float2(0.5f * (Zp.x + Zm.x), 0.5f * (Zp.y - Zm.y));
      float2 yb = make_float2(0.5f * (Zp.y + Zm.y), 0.5f * (Zm.x - Zp.x));
      if (v <= 256) { wA[v] = ya; wB[v] = yb; }
    }
  }
}

// Tiled plane transpose: src[H][W] -> dst[W][H], one plane per blockIdx.z.
__global__ __launch_bounds__(256) void k_transpose(
    const float2* __restrict__ src, float2* __restrict__ dst, int H, int W) {
  __shared__ float2 tile[32][33];
  size_t po = (size_t)blockIdx.z * H * W;
  const float2* s = src + po;
  float2* d = dst + po;
  int tx = threadIdx.x & 31, ty = threadIdx.x >> 5;
  int w0 = blockIdx.x * 32, h0 = blockIdx.y * 32;
  #pragma unroll
  for (int k = 0; k < 4; ++k) {
    int h = h0 + ty + 8 * k, ww = w0 + tx;
    if (h < H && ww < W) tile[ty + 8 * k][tx] = s[(size_t)h * W + ww];
  }
  __syncthreads();
  #pragma unroll
  for (int k = 0; k < 4; ++k) {
    int wr = w0 + ty + 8 * k, hr = h0 + tx;
    if (wr < W && hr < H) d[(size_t)wr * H + hr] = tile[tx][ty + 8 * k];
  }
}

// Fused per-image column pass: fwd FFT + Wiener + inv FFT, on zh2[img][v][row]
// (columns contiguous). One wave per column, in place.
__global__ __launch_bounds__(256) void k_col_wiener(
    float2* __restrict__ zh2, const float2* __restrict__ S, int imgBase) {
  __shared__ float ere[4][EXSZ], eim[4][EXSZ];
  __shared__ float2 tw[512];
  int t = threadIdx.x, w = t >> 6, j = t & 63;
  fill_tw(tw, t);
  __syncthreads();
  int img_l = blockIdx.x / 17, vg = blockIdx.x % 17;
  int img = imgBase + img_l;
  for (int q = 0; q < 4; ++q) {
    int v = vg * 16 + w * 4 + q;
    bool ok = (v <= 256);
    float2* col = zh2 + ((size_t)img_l * NV + (ok ? v : 0)) * FFT_N;
    float2 r[8];
    #pragma unroll
    for (int a = 0; a < 8; ++a) r[a] = ok ? col[64 * a + j] : make_float2(0.f, 0.f);
    fft512_reg<false>(r, ere[w], eim[w], tw, j);
    if (ok) {
      const float2* Sp = S + (size_t)img * KSZ * FFT_N + v;
      float2 sv[KSZ];
      #pragma unroll
      for (int i = 0; i < KSZ; ++i) sv[i] = Sp[(size_t)i * FFT_N];
      float lv = 2.f - 2.f * tw[v].x;
      int u0 = (j >> 3) + 8 * (j & 7);          // fwd-output layout: u = u0+64f
      #pragma unroll
      for (int f = 0; f < 8; ++f) {
        int u = u0 + 64 * f;
        float2 wu = tw[u];
        float2 c7 = tw[(7 * u) & 511];
        float2 cu = make_float2(c7.x, -c7.y);   // e^{+2pi i 7u/512}
        float2 H = make_float2(0.f, 0.f);
        #pragma unroll
        for (int i = 0; i < KSZ; ++i) {
          H.x += cu.x * sv[i].x - cu.y * sv[i].y;
          H.y += cu.x * sv[i].y + cu.y * sv[i].x;
          cu = cmul(cu, wu);
        }
        float lap = (2.f - 2.f * wu.x) + lv;
        float inv = 1.f / (H.x * H.x + H.y * H.y + BAL * lap * lap);
        float2 Z = r[f];
        r[f] = make_float2((H.x * Z.x + H.y * Z.y) * inv,
                           (H.x * Z.y - H.y * Z.x) * inv);
      }
    }
    bitswap_lanes(r, j);                  // -> lane-linear k for the inverse
    fft512_reg<true>(r, ere[w], eim[w], tw, j);
    bitswap_lanes(r, j);                  // -> lane-linear pixels
    if (ok) {
      #pragma unroll
      for (int f = 0; f < 8; ++f) col[64 * f + j] = r[f];
    }
  }
}

// Hermitian repack + inverse row FFT + scale/clip/store both images.
__global__ __launch_bounds__(256) void k_rows_inv(
    const float2* __restrict__ zh1, float* __restrict__ out, int pairBase) {
  __shared__ float ere[4][EXSZ], eim[4][EXSZ];
  __shared__ float2 tw[512];
  int t = threadIdx.x, w = t >> 6, j = t & 63;
  fill_tw(tw, t);
  __syncthreads();
  int p = blockIdx.x >> 5, bg = blockIdx.x & 31;
  int gp = pairBase + p;
  const float2* plA = zh1 + (size_t)(2 * p) * PLANE;
  const float2* plB = plA + PLANE;
  float* baseA = out + (size_t)(2 * gp) * IMG_PIX;
  float* baseB = baseA + IMG_PIX;
  const float sc = 1.f / (float)IMG_PIX;
  for (int q = 0; q < 4; ++q) {
    int row = bg * 16 + q * 4 + w;
    const float2* rA = plA + (size_t)row * NV;
    const float2* rB = plB + (size_t)row * NV;
    float2 r[8];
    #pragma unroll
    for (int a = 0; a < 8; ++a) {
      int n = 64 * a + j;
      if (n <= 256) {
        float2 ya = rA[n], yb = rB[n];
        r[a] = make_float2(ya.x - yb.y, ya.y + yb.x);        // YA + i YB
      } else {
        int n2 = 512 - n;
        float2 ya = rA[n2], yb = rB[n2];
        r[a] = make_float2(ya.x + yb.y, yb.x - ya.y);        // conj(YA)+i conj(YB)
      }
    }
    fft512_reg<true>(r, ere[w], eim[w], tw, j);
    bitswap_lanes(r, j);                  // lane j reg f <-> pixel 64f + j
    float* oA = baseA + (size_t)row * FFT_N;
    float* oB = baseB + (size_t)row * FFT_N;
    #pragma unroll
    for (int f = 0; f < 8; ++f) {
      int px = 64 * f + j;
      oA[px] = fminf(1.f, fmaxf(-1.f, r[f].x * sc));
      oB[px] = fminf(1.f, fmaxf(-1.f, r[f].y * sc));
    }
  }
}

extern "C" void kernel_launch(void* const* d_in, const int* in_sizes, int n_in,
                              void* d_out, int out_size, void* d_ws, size_t ws_size,
                              hipStream_t stream) {
  const float* y       = (const float*)d_in[0];
  const float* filters = (const float*)d_in[1];
  float* out = (float*)d_out;

  // ws: [S: 48*15*512 f2 = 2.95MB][zh1: chunk*2 planes][zh2: chunk*2 planes]
  size_t sElems = (size_t)NIMG * KSZ * FFT_N;
  float2* S = (float2*)d_ws;
  size_t sBytes = sElems * sizeof(float2);
  size_t zBytes = (ws_size > sBytes) ? (ws_size - sBytes) : 0;
  size_t perPair = 4 * PLANE * sizeof(float2);   // zh1+zh2, 2 planes each
  int chunk = (int)(zBytes / perPair);
  if (chunk > NPAIR) chunk = NPAIR;
  if (chunk < 1)     chunk = 1;
  float2* zh1 = S + sElems;
  float2* zh2 = zh1 + (size_t)chunk * 2 * PLANE;

  k_psf_rows<<<NIMG * KSZ, 256, 0, stream>>>(filters, S);

  for (int p0 = 0; p0 < NPAIR; p0 += chunk) {
    int nc = (chunk < NPAIR - p0) ? chunk : (NPAIR - p0);
    k_rows_fwd  <<<nc * 32, 256, 0, stream>>>(y, zh1, p0);
    k_transpose <<<dim3(9, 16, 2 * nc), 256, 0, stream>>>(zh1, zh2, FFT_N, NV);
    k_col_wiener<<<2 * nc * 17, 256, 0, stream>>>(zh2, S, 2 * p0);
    k_transpose <<<dim3(16, 9, 2 * nc), 256, 0, stream>>>(zh2, zh1, NV, FFT_N);
    k_rows_inv  <<<nc * 32, 256, 0, stream>>>(zh1, out, p0);
  }
}